// Round 3
// baseline (75.704 us; speedup 1.0000x reference)
//
#include <hip/hip_runtime.h>
#include <hip/hip_bf16.h>

typedef __bf16 bf16x8 __attribute__((ext_vector_type(8)));
typedef __bf16 bf16x4 __attribute__((ext_vector_type(4)));
typedef float  f32x4  __attribute__((ext_vector_type(4)));

#define N_BASIS   512
#define FRAME_LEN 64
#define BATCH     8
#define FRAMES    16000
#define STEP      32
#define OUT_PER_BATCH (STEP * (FRAMES - 1) + FRAME_LEN)   // 512032

#define WAVES            8
#define BLOCK            (WAVES * 64)                 // 512 threads
#define FPB              (WAVES * 16)                 // frames per tile = 128
#define TPBATCH          (FRAMES / FPB)               // 125 tiles per batch
#define TOTAL_TILES      (BATCH * TPBATCH)            // 1000
#define TILES_PER_BLOCK  2
#define GRID             (TOTAL_TILES / TILES_PER_BLOCK)  // 500

// ---------------------------------------------------------------------------
// prep: f32 basis (64x512, row-major) -> bf16 MFMA-B fragments in d_ws.
// Fragment fr = ks*4 + nt occupies 1KB at wsb + fr*512 elems; within it,
// lane l elem j = basis[nt*16 + (l&15)][ks*32 + (l>>4)*8 + j]  (exactly the
// mfma_f32_16x16x32_bf16 B operand this kernel's compute loop consumes).
// ---------------------------------------------------------------------------
__global__ __launch_bounds__(256)
void prep_basis(const float* __restrict__ basis, __bf16* __restrict__ wsb) {
    const int t  = blockIdx.x * blockDim.x + threadIdx.x;  // 0..4095
    const int fr = t >> 6;
    const int l  = t & 63;
    const int c  = (fr & 3) * 16 + (l & 15);
    const int n  = (fr >> 2) * 32 + (l >> 4) * 8;
    const float4 a0 = *(const float4*)(basis + c * N_BASIS + n);
    const float4 a1 = *(const float4*)(basis + c * N_BASIS + n + 4);
    bf16x8 b;
    b[0] = (__bf16)a0.x; b[1] = (__bf16)a0.y;
    b[2] = (__bf16)a0.z; b[3] = (__bf16)a0.w;
    b[4] = (__bf16)a1.x; b[5] = (__bf16)a1.y;
    b[6] = (__bf16)a1.z; b[7] = (__bf16)a1.w;
    *(bf16x8*)(wsb + (size_t)t * 8) = b;
}

// ---------------------------------------------------------------------------
// C[f][c] = sum_n weight[f][n] * W[c][n]; out[b][32f + c] = C[f][c] + C[f-1][c+32].
// B-fragments come straight from d_ws (L2-resident, coalesced 1KB loads) —
// no LDS staging, no initial barrier: HBM weight streaming starts at cycle 0.
// Every output sample is ONE plain store:
//   - thread-local merge for r>=1 (partner acc[nt+2][r-1] in same thread)
//   - __shfl_up(16) for r==0, hi>=1
//   - 2KB LDS xbuf for r==0, hi==0 (previous wave / previous tile)
//   - f32 VALU carry row (wave 0) for the block's first tile boundary
// ---------------------------------------------------------------------------
__global__ __launch_bounds__(BLOCK, 4)
void basis_ola_kernel(const float* __restrict__ weight,
                      const float* __restrict__ basis,
                      const __bf16* __restrict__ wsb,
                      float* __restrict__ out)
{
    __shared__ float xbuf[2][WAVES][2][16];           // 2 KiB, tile-parity dbuf

    const int tid  = threadIdx.x;
    const int wave = tid >> 6;
    const int lane = tid & 63;
    const int lo   = lane & 15;
    const int hi   = lane >> 4;

    const int g0 = blockIdx.x * TILES_PER_BLOCK;

    // ---- carry for the block's FIRST tile boundary (wave 0 only, f32 exact,
    //      no dependence on any staged data; other waves proceed immediately).
    //      xbuf[1][7][nt][lo] := C[F0-1][16*(nt+2)+lo] for tile g0.
    if (wave == 0) {
        const int bb0 = g0 / TPBATCH, t0 = g0 % TPBATCH;
        float val = 0.f;
        if (t0 > 0) {
            const int c  = 32 + (lane >> 1);          // basis row 32..63
            const int kh = (lane & 1) * 256;          // half of K per lane
            const float* wr = weight + ((size_t)bb0 * FRAMES + (size_t)t0 * FPB - 1) * N_BASIS;
            const float* br = basis + (size_t)c * N_BASIS;
            for (int n = kh; n < kh + 256; n += 4) {
                const float4 a = *(const float4*)(wr + n);
                const float4 w = *(const float4*)(br + n);
                val += a.x * w.x + a.y * w.y + a.z * w.z + a.w * w.w;
            }
        }
        val += __shfl_xor(val, 1);
        if ((lane & 1) == 0) {
            const int cc = lane >> 1;                 // 0..31  (c-32)
            xbuf[1][WAVES - 1][cc >> 4][cc & 15] = val;
        }
    }

    for (int ti = 0; ti < TILES_PER_BLOCK; ++ti) {
        const int g    = g0 + ti;
        const int bb   = g / TPBATCH;
        const int tile = g % TPBATCH;
        const int F0   = tile * FPB;
        const int p    = ti & 1;

        // A-fragment row (mfma_f32_16x16x32_bf16: row = lane&15, k = (lane>>4)*8 + j)
        const float* arow = weight +
            ((size_t)bb * FRAMES + F0 + wave * 16 + lo) * (size_t)N_BASIS;

        f32x4 acc[4] = {};   // nt -> columns nt*16 + lo

        #pragma unroll 2
        for (int ks = 0; ks < N_BASIS / 32; ++ks) {
            const int kk = ks * 32;
            const float4 a0 = *(const float4*)(arow + kk + hi * 8);
            const float4 a1 = *(const float4*)(arow + kk + hi * 8 + 4);
            bf16x8 af;
            af[0] = (__bf16)a0.x; af[1] = (__bf16)a0.y;
            af[2] = (__bf16)a0.z; af[3] = (__bf16)a0.w;
            af[4] = (__bf16)a1.x; af[5] = (__bf16)a1.y;
            af[6] = (__bf16)a1.z; af[7] = (__bf16)a1.w;

            const __bf16* fb = wsb + (size_t)(ks * 4) * 512 + lane * 8;
            #pragma unroll
            for (int nt = 0; nt < 4; ++nt) {
                const bf16x8 bfr = *(const bf16x8*)(fb + nt * 512);
                acc[nt] = __builtin_amdgcn_mfma_f32_16x16x32_bf16(af, bfr, acc[nt], 0, 0, 0);
            }
        }

        // ---- exchange: hi==3 lanes publish trailing values ----
        // acc[nt+2][3] = C[F0+16w+15][16*(nt+2)+lo]
        if (hi == 3) {
            xbuf[p][wave][0][lo] = acc[2][3];
            xbuf[p][wave][1][lo] = acc[3][3];
        }
        __syncthreads();

        // ---- fused OLA epilogue, plain stores only ----
        float* ob = out + (size_t)bb * OUT_PER_BATCH;
        const int fbase = F0 + wave * 16 + hi * 4;

        #pragma unroll
        for (int nt = 0; nt < 2; ++nt) {
            // r == 0: partner C[fbase-1][16*(nt+2)+lo]
            const float up = __shfl_up(acc[nt + 2][3], 16);   // all lanes execute
            float pv;
            if (hi > 0)          pv = up;
            else if (wave > 0)   pv = xbuf[p][wave - 1][nt][lo];
            else if (tile > 0)   pv = xbuf[p ^ 1][WAVES - 1][nt][lo];
            else                 pv = 0.f;
            ob[32 * fbase + nt * 16 + lo] = acc[nt][0] + pv;

            #pragma unroll
            for (int r = 1; r < 4; ++r) {
                ob[32 * (fbase + r) + nt * 16 + lo] = acc[nt][r] + acc[nt + 2][r - 1];
            }
        }

        // last tile of a batch: trailing 32 samples get only C[15999][c+32]
        if (tile == TPBATCH - 1 && wave == WAVES - 1 && hi == 3) {
            ob[32 * FRAMES + 0 * 16 + lo] = acc[2][3];
            ob[32 * FRAMES + 1 * 16 + lo] = acc[3][3];
        }

        __syncthreads();   // protect xbuf of this parity before next tile reuses
    }
}

extern "C" void kernel_launch(void* const* d_in, const int* in_sizes, int n_in,
                              void* d_out, int out_size, void* d_ws, size_t ws_size,
                              hipStream_t stream) {
    const float* weight = (const float*)d_in[0];   // (8, 16000, 512) f32
    const float* basis  = (const float*)d_in[1];   // (64, 512) f32
    float* out = (float*)d_out;                    // (8, 512032) f32
    __bf16* wsb = (__bf16*)d_ws;                   // 64 KiB bf16 B-fragments

    prep_basis<<<16, 256, 0, stream>>>(basis, wsb);
    basis_ola_kernel<<<GRID, BLOCK, 0, stream>>>(weight, basis, wsb, out);
}

// Round 4
// 65.565 us; speedup vs baseline: 1.1546x; 1.1546x over previous
//
#include <hip/hip_runtime.h>
#include <hip/hip_bf16.h>

typedef __bf16 bf16x8 __attribute__((ext_vector_type(8)));
typedef float  f32x4  __attribute__((ext_vector_type(4)));

#define N_BASIS   512
#define FRAME_LEN 64
#define BATCH     8
#define FRAMES    16000
#define STEP      32
#define OUT_PER_BATCH (STEP * (FRAMES - 1) + FRAME_LEN)   // 512032

#define WAVES            8
#define BLOCK            (WAVES * 64)                 // 512 threads
#define FPB              (WAVES * 16)                 // frames per tile = 128
#define TPBATCH          (FRAMES / FPB)               // 125
#define TOTAL_TILES      (BATCH * TPBATCH)            // 1000
#define TILES_PER_BLOCK  2
#define GRID             (TOTAL_TILES / TILES_PER_BLOCK)  // 500

__device__ __forceinline__ f32x4 ldnt(const float* p) {
    return __builtin_nontemporal_load((const f32x4*)p);
}

// one MFMA K-step (K=32): af from two f32x4 of weight row, B from swizzled LDS
__device__ __forceinline__ void kstep(const f32x4 a0, const f32x4 a1,
                                      const __bf16* W, int kk, int lo, int hi,
                                      f32x4 acc[4]) {
    bf16x8 af;
    af[0] = (__bf16)a0[0]; af[1] = (__bf16)a0[1];
    af[2] = (__bf16)a0[2]; af[3] = (__bf16)a0[3];
    af[4] = (__bf16)a1[0]; af[5] = (__bf16)a1[1];
    af[6] = (__bf16)a1[2]; af[7] = (__bf16)a1[3];
    #pragma unroll
    for (int nt = 0; nt < 4; ++nt) {
        const int c = nt * 16 + lo;
        int e = (c << 9) + kk + hi * 8;
        e ^= (c & 7) << 3;                       // bank-conflict swizzle
        const bf16x8 b = *(const bf16x8*)(&W[e]);
        acc[nt] = __builtin_amdgcn_mfma_f32_16x16x32_bf16(af, b, acc[nt], 0, 0, 0);
    }
}

// full K for one tile; q0..q3 are the pre-issued loads for ks=0,1
__device__ __forceinline__ void tile_compute(const float* __restrict__ arow,
                                             const __bf16* W,
                                             const f32x4 q0, const f32x4 q1,
                                             const f32x4 q2, const f32x4 q3,
                                             int lo, int hi, f32x4 acc[4]) {
    kstep(q0, q1, W, 0,  lo, hi, acc);
    kstep(q2, q3, W, 32, lo, hi, acc);
    #pragma unroll 2
    for (int ks = 2; ks < 16; ++ks) {
        const int kk = ks * 32;
        const f32x4 a0 = ldnt(arow + kk + hi * 8);
        const f32x4 a1 = ldnt(arow + kk + hi * 8 + 4);
        kstep(a0, a1, W, kk, lo, hi, acc);
    }
}

// fused OLA epilogue: every output sample exactly one plain (NT) store
__device__ __forceinline__ void epilogue(const f32x4 acc[4],
                                         float* __restrict__ out,
                                         float (&xbuf)[2][WAVES][2][16],
                                         int P, int tile, int bb, int F0,
                                         int wave, int lo, int hi) {
    if (hi == 3) {                                 // publish trailing row
        xbuf[P][wave][0][lo] = acc[2][3];
        xbuf[P][wave][1][lo] = acc[3][3];
    }
    __syncthreads();

    float* ob = out + (size_t)bb * OUT_PER_BATCH;
    const int fbase = F0 + wave * 16 + hi * 4;

    #pragma unroll
    for (int nt = 0; nt < 2; ++nt) {
        const float up = __shfl_up(acc[nt + 2][3], 16);   // all lanes execute
        float pv;
        if (hi > 0)          pv = up;
        else if (wave > 0)   pv = xbuf[P][wave - 1][nt][lo];
        else if (tile > 0)   pv = xbuf[P ^ 1][WAVES - 1][nt][lo];
        else                 pv = 0.f;
        __builtin_nontemporal_store(acc[nt][0] + pv, &ob[32 * fbase + nt * 16 + lo]);
        #pragma unroll
        for (int r = 1; r < 4; ++r)
            __builtin_nontemporal_store(acc[nt][r] + acc[nt + 2][r - 1],
                                        &ob[32 * (fbase + r) + nt * 16 + lo]);
    }

    // last tile of a batch: trailing 32 samples have only one contributor
    if (tile == TPBATCH - 1 && wave == WAVES - 1 && hi == 3) {
        __builtin_nontemporal_store(acc[2][3], &ob[32 * FRAMES + lo]);
        __builtin_nontemporal_store(acc[3][3], &ob[32 * FRAMES + 16 + lo]);
    }
}

__global__ __launch_bounds__(BLOCK, 4)
void basis_ola_kernel(const float* __restrict__ weight,
                      const float* __restrict__ basis,
                      float* __restrict__ out)
{
    __shared__ __bf16 Wlds[FRAME_LEN * N_BASIS];   // 64 KiB, swizzled bf16
    __shared__ float  xbuf[2][WAVES][2][16];       // 2 KiB OLA exchange

    const int tid  = threadIdx.x;
    const int wave = tid >> 6;
    const int lane = tid & 63;
    const int lo   = lane & 15;
    const int hi   = lane >> 4;

    const int g0  = blockIdx.x * TILES_PER_BLOCK;
    const int bb0 = g0 / TPBATCH, t0 = g0 % TPBATCH;
    const int g1  = g0 + 1;
    const int bb1 = g1 / TPBATCH, t1 = g1 % TPBATCH;

    // ---- tile 0 A-prefetch (ks=0,1) BEFORE staging: HBM busy from cycle 0 ----
    const float* arow0 = weight + ((size_t)bb0 * FRAMES + t0 * FPB + wave * 16 + lo) * N_BASIS;
    f32x4 q0 = ldnt(arow0 + hi * 8);
    f32x4 q1 = ldnt(arow0 + hi * 8 + 4);
    f32x4 q2 = ldnt(arow0 + 32 + hi * 8);
    f32x4 q3 = ldnt(arow0 + 32 + hi * 8 + 4);

    // ---- stage basis f32 -> bf16 LDS (swizzle e ^= (c&7)<<3), 8 iters ----
    for (int q = tid; q < (FRAME_LEN * N_BASIS) / 8; q += BLOCK) {
        const int e = q * 8;
        const int c = e >> 9;
        const f32x4 v0 = *(const f32x4*)(basis + e);
        const f32x4 v1 = *(const f32x4*)(basis + e + 4);
        bf16x8 b;
        b[0] = (__bf16)v0[0]; b[1] = (__bf16)v0[1];
        b[2] = (__bf16)v0[2]; b[3] = (__bf16)v0[3];
        b[4] = (__bf16)v1[0]; b[5] = (__bf16)v1[1];
        b[6] = (__bf16)v1[2]; b[7] = (__bf16)v1[3];
        *(bf16x8*)(&Wlds[e ^ ((c & 7) << 3)]) = b;
    }

    // ---- carry for block's first boundary (wave 0, f32 exact) ----
    // xbuf[1][7][nt][lo] := C[F0-1][16*(nt+2)+lo] for tile g0
    if (wave == 0) {
        float val = 0.f;
        if (t0 > 0) {
            const int c  = 32 + (lane >> 1);
            const int kh = (lane & 1) * 256;
            const float* wr = weight + ((size_t)bb0 * FRAMES + (size_t)t0 * FPB - 1) * N_BASIS;
            const float* br = basis + (size_t)c * N_BASIS;
            #pragma unroll 4
            for (int n = kh; n < kh + 256; n += 4) {
                const f32x4 a = *(const f32x4*)(wr + n);
                const f32x4 w = *(const f32x4*)(br + n);
                val += a[0]*w[0] + a[1]*w[1] + a[2]*w[2] + a[3]*w[3];
            }
        }
        val += __shfl_xor(val, 1);
        if ((lane & 1) == 0) {
            const int cc = lane >> 1;
            xbuf[1][WAVES - 1][cc >> 4][cc & 15] = val;
        }
    }
    __syncthreads();

    // ================= tile 0 =================
    f32x4 acc0[4] = {};
    tile_compute(arow0, Wlds, q0, q1, q2, q3, lo, hi, acc0);

    // issue tile 1's first loads BEFORE tile 0's epilogue barriers:
    // they stay in flight across the barrier, keeping HBM streaming
    const float* arow1 = weight + ((size_t)bb1 * FRAMES + t1 * FPB + wave * 16 + lo) * N_BASIS;
    q0 = ldnt(arow1 + hi * 8);
    q1 = ldnt(arow1 + hi * 8 + 4);
    q2 = ldnt(arow1 + 32 + hi * 8);
    q3 = ldnt(arow1 + 32 + hi * 8 + 4);

    epilogue(acc0, out, xbuf, /*P=*/0, t0, bb0, t0 * FPB, wave, lo, hi);
    __syncthreads();   // protect xbuf[1] pre-carry slot until consumed above

    // ================= tile 1 =================
    f32x4 acc1[4] = {};
    tile_compute(arow1, Wlds, q0, q1, q2, q3, lo, hi, acc1);
    epilogue(acc1, out, xbuf, /*P=*/1, t1, bb1, t1 * FPB, wave, lo, hi);
}

extern "C" void kernel_launch(void* const* d_in, const int* in_sizes, int n_in,
                              void* d_out, int out_size, void* d_ws, size_t ws_size,
                              hipStream_t stream) {
    const float* weight = (const float*)d_in[0];   // (8, 16000, 512) f32
    const float* basis  = (const float*)d_in[1];   // (64, 512) f32
    float* out = (float*)d_out;                    // (8, 512032) f32

    basis_ola_kernel<<<GRID, BLOCK, 0, stream>>>(weight, basis, out);
}

// Round 5
// 57.595 us; speedup vs baseline: 1.3144x; 1.1384x over previous
//
#include <hip/hip_runtime.h>
#include <hip/hip_bf16.h>

typedef __bf16 bf16x8 __attribute__((ext_vector_type(8)));
typedef float  f32x4  __attribute__((ext_vector_type(4)));

#define N_BASIS   512
#define FRAME_LEN 64
#define BATCH     8
#define FRAMES    16000
#define STEP      32
#define OUT_PER_BATCH (STEP * (FRAMES - 1) + FRAME_LEN)   // 512032

#define WAVES            8
#define BLOCK            (WAVES * 64)                 // 512 threads
#define FPB              (WAVES * 16)                 // frames per tile = 128
#define TPBATCH          (FRAMES / FPB)               // 125
#define TOTAL_TILES      (BATCH * TPBATCH)            // 1000
#define TILES_PER_BLOCK  2
#define GRID             (TOTAL_TILES / TILES_PER_BLOCK)  // 500

// one MFMA K-step (K=32): A-frag packed from two f32x4, B from swizzled LDS
__device__ __forceinline__ void kstep(const f32x4 a0, const f32x4 a1,
                                      const __bf16* W, int kk, int lo, int hi,
                                      f32x4 acc[4]) {
    bf16x8 af;
    af[0] = (__bf16)a0[0]; af[1] = (__bf16)a0[1];
    af[2] = (__bf16)a0[2]; af[3] = (__bf16)a0[3];
    af[4] = (__bf16)a1[0]; af[5] = (__bf16)a1[1];
    af[6] = (__bf16)a1[2]; af[7] = (__bf16)a1[3];
    #pragma unroll
    for (int nt = 0; nt < 4; ++nt) {
        const int c = nt * 16 + lo;
        int e = (c << 9) + kk + hi * 8;
        e ^= (c & 7) << 3;                       // bank-conflict swizzle
        const bf16x8 b = *(const bf16x8*)(&W[e]);
        acc[nt] = __builtin_amdgcn_mfma_f32_16x16x32_bf16(af, b, acc[nt], 0, 0, 0);
    }
}

__global__ __launch_bounds__(BLOCK, 4)
void basis_ola_kernel(const float* __restrict__ weight,
                      const float* __restrict__ basis,
                      float* __restrict__ out)
{
    __shared__ __bf16 Wlds[FRAME_LEN * N_BASIS];   // 64 KiB, swizzled bf16
    __shared__ float  xbuf[2][WAVES][2][16];       // 2 KiB OLA exchange

    const int tid  = threadIdx.x;
    const int wave = tid >> 6;
    const int lane = tid & 63;
    const int lo   = lane & 15;
    const int hi   = lane >> 4;

    const int g0 = blockIdx.x * TILES_PER_BLOCK;

    // ---- tile-0 A prefetch (ks=0,1) BEFORE staging: HBM busy from cycle 0 ----
    const float* arow = weight +
        ((size_t)(g0 / TPBATCH) * FRAMES + (g0 % TPBATCH) * FPB + wave * 16 + lo) * N_BASIS;
    f32x4 q0 = *(const f32x4*)(arow + hi * 8);
    f32x4 q1 = *(const f32x4*)(arow + hi * 8 + 4);
    f32x4 q2 = *(const f32x4*)(arow + 32 + hi * 8);
    f32x4 q3 = *(const f32x4*)(arow + 32 + hi * 8 + 4);

    // ---- stage basis f32 -> bf16 LDS (swizzle e ^= (c&7)<<3), 8 iters ----
    for (int q = tid; q < (FRAME_LEN * N_BASIS) / 8; q += BLOCK) {
        const int e = q * 8;
        const int c = e >> 9;
        const f32x4 v0 = *(const f32x4*)(basis + e);
        const f32x4 v1 = *(const f32x4*)(basis + e + 4);
        bf16x8 b;
        b[0] = (__bf16)v0[0]; b[1] = (__bf16)v0[1];
        b[2] = (__bf16)v0[2]; b[3] = (__bf16)v0[3];
        b[4] = (__bf16)v1[0]; b[5] = (__bf16)v1[1];
        b[6] = (__bf16)v1[2]; b[7] = (__bf16)v1[3];
        *(bf16x8*)(&Wlds[e ^ ((c & 7) << 3)]) = b;
    }

    // ---- carry for block's first boundary (wave 0, f32 exact) ----
    // xbuf[1][7][nt][lo] := C[F0-1][16*(nt+2)+lo] for tile g0
    if (wave == 0) {
        const int bb0 = g0 / TPBATCH, t0 = g0 % TPBATCH;
        float val = 0.f;
        if (t0 > 0) {
            const int c  = 32 + (lane >> 1);
            const int kh = (lane & 1) * 256;
            const float* wr = weight + ((size_t)bb0 * FRAMES + (size_t)t0 * FPB - 1) * N_BASIS;
            const float* br = basis + (size_t)c * N_BASIS;
            #pragma unroll 4
            for (int n = kh; n < kh + 256; n += 4) {
                const f32x4 a = *(const f32x4*)(wr + n);
                const f32x4 w = *(const f32x4*)(br + n);
                val += a[0]*w[0] + a[1]*w[1] + a[2]*w[2] + a[3]*w[3];
            }
        }
        val += __shfl_xor(val, 1);
        if ((lane & 1) == 0) {
            const int cc = lane >> 1;
            xbuf[1][WAVES - 1][cc >> 4][cc & 15] = val;
        }
    }
    __syncthreads();

    for (int ti = 0; ti < TILES_PER_BLOCK; ++ti) {
        const int g    = g0 + ti;
        const int bb   = g / TPBATCH;
        const int tile = g % TPBATCH;
        const int F0   = tile * FPB;
        const int P    = ti & 1;

        f32x4 acc[4] = {};

        // ks = 0,1 from the prefetched registers
        kstep(q0, q1, Wlds, 0,  lo, hi, acc);
        kstep(q2, q3, Wlds, 32, lo, hi, acc);

        #pragma unroll 2
        for (int ks = 2; ks < 16; ++ks) {
            const int kk = ks * 32;
            const f32x4 a0 = *(const f32x4*)(arow + kk + hi * 8);
            const f32x4 a1 = *(const f32x4*)(arow + kk + hi * 8 + 4);
            kstep(a0, a1, Wlds, kk, lo, hi, acc);
        }

        // ---- prefetch NEXT tile's ks=0,1 before the epilogue barriers ----
        // (only for this block's own next tile; avoids duplicate HBM fetch)
        if (ti + 1 < TILES_PER_BLOCK) {
            const int gn = g + 1;
            arow = weight +
                ((size_t)(gn / TPBATCH) * FRAMES + (gn % TPBATCH) * FPB + wave * 16 + lo) * N_BASIS;
            q0 = *(const f32x4*)(arow + hi * 8);
            q1 = *(const f32x4*)(arow + hi * 8 + 4);
            q2 = *(const f32x4*)(arow + 32 + hi * 8);
            q3 = *(const f32x4*)(arow + 32 + hi * 8 + 4);
        }

        // ---- exchange: hi==3 lanes publish trailing values ----
        if (hi == 3) {
            xbuf[P][wave][0][lo] = acc[2][3];
            xbuf[P][wave][1][lo] = acc[3][3];
        }
        __syncthreads();

        // ---- fused OLA epilogue, plain stores only ----
        float* ob = out + (size_t)bb * OUT_PER_BATCH;
        const int fbase = F0 + wave * 16 + hi * 4;

        #pragma unroll
        for (int nt = 0; nt < 2; ++nt) {
            const float up = __shfl_up(acc[nt + 2][3], 16);   // all lanes execute
            float pv;
            if (hi > 0)          pv = up;
            else if (wave > 0)   pv = xbuf[P][wave - 1][nt][lo];
            else if (tile > 0)   pv = xbuf[P ^ 1][WAVES - 1][nt][lo];
            else                 pv = 0.f;
            ob[32 * fbase + nt * 16 + lo] = acc[nt][0] + pv;

            #pragma unroll
            for (int r = 1; r < 4; ++r)
                ob[32 * (fbase + r) + nt * 16 + lo] = acc[nt][r] + acc[nt + 2][r - 1];
        }

        // last tile of a batch: trailing 32 samples have only one contributor
        if (tile == TPBATCH - 1 && wave == WAVES - 1 && hi == 3) {
            ob[32 * FRAMES + lo]      = acc[2][3];
            ob[32 * FRAMES + 16 + lo] = acc[3][3];
        }

        __syncthreads();   // xbuf parity slot must be consumed before reuse
    }
}

extern "C" void kernel_launch(void* const* d_in, const int* in_sizes, int n_in,
                              void* d_out, int out_size, void* d_ws, size_t ws_size,
                              hipStream_t stream) {
    const float* weight = (const float*)d_in[0];   // (8, 16000, 512) f32
    const float* basis  = (const float*)d_in[1];   // (64, 512) f32
    float* out = (float*)d_out;                    // (8, 512032) f32

    basis_ola_kernel<<<GRID, BLOCK, 0, stream>>>(weight, basis, out);
}

// Round 6
// 56.530 us; speedup vs baseline: 1.3392x; 1.0188x over previous
//
#include <hip/hip_runtime.h>
#include <hip/hip_bf16.h>

typedef __bf16 bf16x8 __attribute__((ext_vector_type(8)));
typedef float  f32x4  __attribute__((ext_vector_type(4)));

#define N_BASIS   512
#define FRAME_LEN 64
#define BATCH     8
#define FRAMES    16000
#define STEP      32
#define OUT_PER_BATCH (STEP * (FRAMES - 1) + FRAME_LEN)   // 512032

#define WAVES            8
#define BLOCK            (WAVES * 64)                 // 512 threads
#define FPB              (WAVES * 16)                 // frames per tile = 128
#define TPBATCH          (FRAMES / FPB)               // 125
#define TOTAL_TILES      (BATCH * TPBATCH)            // 1000
#define TILES_PER_BLOCK  2
#define GRID             (TOTAL_TILES / TILES_PER_BLOCK)  // 500

// one MFMA K-step (K=32): A-frag packed from two f32x4, B from swizzled LDS
__device__ __forceinline__ void kstep(const f32x4 a0, const f32x4 a1,
                                      const __bf16* W, int kk, int lo, int hi,
                                      f32x4 acc[4]) {
    bf16x8 af;
    af[0] = (__bf16)a0[0]; af[1] = (__bf16)a0[1];
    af[2] = (__bf16)a0[2]; af[3] = (__bf16)a0[3];
    af[4] = (__bf16)a1[0]; af[5] = (__bf16)a1[1];
    af[6] = (__bf16)a1[2]; af[7] = (__bf16)a1[3];
    #pragma unroll
    for (int nt = 0; nt < 4; ++nt) {
        const int c = nt * 16 + lo;
        int e = (c << 9) + kk + hi * 8;
        e ^= (c & 7) << 3;                       // bank-conflict swizzle
        const bf16x8 b = *(const bf16x8*)(&W[e]);
        acc[nt] = __builtin_amdgcn_mfma_f32_16x16x32_bf16(af, b, acc[nt], 0, 0, 0);
    }
}

__global__ __launch_bounds__(BLOCK, 4)
void basis_ola_kernel(const float* __restrict__ weight,
                      const float* __restrict__ basis,
                      float* __restrict__ out)
{
    __shared__ __bf16 Wlds[FRAME_LEN * N_BASIS];   // 64 KiB, swizzled bf16
    __shared__ float  xbuf[2][WAVES][2][16];       // 2 KiB OLA exchange

    const int tid  = threadIdx.x;
    const int wave = tid >> 6;
    const int lane = tid & 63;
    const int lo   = lane & 15;
    const int hi   = lane >> 4;

    const int g0  = blockIdx.x * TILES_PER_BLOCK;
    const int bb0 = g0 / TPBATCH, t0 = g0 % TPBATCH;

    // ---- carry for block's first boundary, PARALLEL across all 512 threads.
    // xbuf[1][7][nt][lo] := C[F0-1][16*(nt+2)+lo] for tile g0 (f32 exact).
    // Thread t dots chunk (t&15) of col 32+(t>>4): 8x16B loads + 32 FMA,
    // then a 16-lane shfl_xor tree reduce. (vs R2: 64 serial iters on wave 0)
    {
        float val = 0.f;
        if (t0 > 0) {
            const float* wr = weight +
                ((size_t)bb0 * FRAMES + (size_t)t0 * FPB - 1) * N_BASIS + (tid & 15) * 32;
            const float* br = basis + (size_t)(32 + (tid >> 4)) * N_BASIS + (tid & 15) * 32;
            #pragma unroll
            for (int n = 0; n < 32; n += 4) {
                const f32x4 a = *(const f32x4*)(wr + n);
                const f32x4 w = *(const f32x4*)(br + n);
                val += a[0]*w[0] + a[1]*w[1] + a[2]*w[2] + a[3]*w[3];
            }
        }
        val += __shfl_xor(val, 1);
        val += __shfl_xor(val, 2);
        val += __shfl_xor(val, 4);
        val += __shfl_xor(val, 8);
        if ((tid & 15) == 0) {
            const int cc = tid >> 4;               // 0..31 (= col - 32)
            xbuf[1][WAVES - 1][cc >> 4][cc & 15] = val;
        }
    }

    // ---- stage basis f32 -> bf16 LDS (swizzle e ^= (c&7)<<3), 8 iters ----
    for (int q = tid; q < (FRAME_LEN * N_BASIS) / 8; q += BLOCK) {
        const int e = q * 8;
        const int c = e >> 9;
        const f32x4 v0 = *(const f32x4*)(basis + e);
        const f32x4 v1 = *(const f32x4*)(basis + e + 4);
        bf16x8 b;
        b[0] = (__bf16)v0[0]; b[1] = (__bf16)v0[1];
        b[2] = (__bf16)v0[2]; b[3] = (__bf16)v0[3];
        b[4] = (__bf16)v1[0]; b[5] = (__bf16)v1[1];
        b[6] = (__bf16)v1[2]; b[7] = (__bf16)v1[3];
        *(bf16x8*)(&Wlds[e ^ ((c & 7) << 3)]) = b;
    }
    __syncthreads();

    for (int ti = 0; ti < TILES_PER_BLOCK; ++ti) {
        const int g    = g0 + ti;
        const int bb   = g / TPBATCH;
        const int tile = g % TPBATCH;
        const int F0   = tile * FPB;
        const int P    = ti & 1;

        const float* arow = weight +
            ((size_t)bb * FRAMES + F0 + wave * 16 + lo) * N_BASIS;

        f32x4 acc[4] = {};

        #pragma unroll 2
        for (int ks = 0; ks < 16; ++ks) {
            const int kk = ks * 32;
            const f32x4 a0 = *(const f32x4*)(arow + kk + hi * 8);
            const f32x4 a1 = *(const f32x4*)(arow + kk + hi * 8 + 4);
            kstep(a0, a1, Wlds, kk, lo, hi, acc);
        }

        // ---- exchange: hi==3 lanes publish trailing values ----
        if (hi == 3) {
            xbuf[P][wave][0][lo] = acc[2][3];
            xbuf[P][wave][1][lo] = acc[3][3];
        }
        __syncthreads();

        // ---- fused OLA epilogue, plain stores only ----
        float* ob = out + (size_t)bb * OUT_PER_BATCH;
        const int fbase = F0 + wave * 16 + hi * 4;

        #pragma unroll
        for (int nt = 0; nt < 2; ++nt) {
            const float up = __shfl_up(acc[nt + 2][3], 16);   // all lanes execute
            float pv;
            if (hi > 0)          pv = up;
            else if (wave > 0)   pv = xbuf[P][wave - 1][nt][lo];
            else if (tile > 0)   pv = xbuf[P ^ 1][WAVES - 1][nt][lo];
            else                 pv = 0.f;
            ob[32 * fbase + nt * 16 + lo] = acc[nt][0] + pv;

            #pragma unroll
            for (int r = 1; r < 4; ++r)
                ob[32 * (fbase + r) + nt * 16 + lo] = acc[nt][r] + acc[nt + 2][r - 1];
        }

        // last tile of a batch: trailing 32 samples have only one contributor
        if (tile == TPBATCH - 1 && wave == WAVES - 1 && hi == 3) {
            ob[32 * FRAMES + lo]      = acc[2][3];
            ob[32 * FRAMES + 16 + lo] = acc[3][3];
        }

        // needed after tile 0 only: tile 1's publish overwrites xbuf[1][7],
        // which tile 0's epilogue just consumed (pre-carry slot)
        if (ti + 1 < TILES_PER_BLOCK) __syncthreads();
    }
}

extern "C" void kernel_launch(void* const* d_in, const int* in_sizes, int n_in,
                              void* d_out, int out_size, void* d_ws, size_t ws_size,
                              hipStream_t stream) {
    const float* weight = (const float*)d_in[0];   // (8, 16000, 512) f32
    const float* basis  = (const float*)d_in[1];   // (64, 512) f32
    float* out = (float*)d_out;                    // (8, 512032) f32

    basis_ola_kernel<<<GRID, BLOCK, 0, stream>>>(weight, basis, out);
}